// Round 7
// baseline (2149.586 us; speedup 1.0000x reference)
//
#include <hip/hip_runtime.h>

namespace {

constexpr int NROWS = 256, LSTEPS = 512, IN = 64, LAT = 32, HID = 128;
constexpr int BROWS = 16;                 // batch rows per block
constexpr int NBLK  = NROWS / BROWS;      // 16 blocks

typedef _Float16 f16x8 __attribute__((ext_vector_type(8)));
typedef float    f32x4 __attribute__((ext_vector_type(4)));

__device__ __forceinline__ float fast_sigmoid(float x) {
    return __fdividef(1.f, 1.f + __expf(-x));
}
__device__ __forceinline__ float fast_softplus(float x) {
    return fmaxf(x, 0.f) + __logf(1.f + __expf(-fabsf(x)));
}
__device__ __forceinline__ float fast_tanh(float x) {
    float e = __expf(-2.f * fabsf(x));
    return copysignf(__fdividef(1.f - e, 1.f + e), x);
}
__device__ __forceinline__ f32x4 MF(f16x8 a, f16x8 b, f32x4 c) {
    return __builtin_amdgcn_mfma_f32_16x16x32_f16(a, b, c, 0, 0, 0);
}
// Pack one B-fragment (32x16 K-major tile) slice for this lane:
// lane supplies B[k0 + 8*g4 + j][col], j=0..7, from row-major W[K][M].
__device__ __forceinline__ f16x8 pack_tile(const float* __restrict__ W, int M,
                                           int k0, int col, int g4) {
    f16x8 v;
#pragma unroll
    for (int j = 0; j < 8; ++j) v[j] = (_Float16)W[(k0 + 8 * g4 + j) * M + col];
    return v;
}

} // namespace

// 16 rows/block, 16 waves. MFMA everywhere; h state exact f32 in gate-lane regs.
// Waves 0-7: gate-waves (own 16 h-units each): gh (A), gi_z (B), gi_x + gates (C).
// Waves 8-9: qzcx -> z (A).  Waves 10-13: pxcz h-part (A), z-part + x_gen (B).
// Waves 14-15: stage next-step X into f16 LDS (A).
__global__ __launch_bounds__(1024) void vrnn_kernel(
    const float* __restrict__ X, const float* __restrict__ EZ, const float* __restrict__ EX,
    const float* __restrict__ Wq, const float* __restrict__ bq,
    const float* __restrict__ Wp, const float* __restrict__ bp,
    const float* __restrict__ Wih, const float* __restrict__ Whh,
    const float* __restrict__ bih, const float* __restrict__ bhh,
    float* __restrict__ out)
{
    // A-operand activation buffers, [row][feat], padded strides (bank-spread).
    __shared__ alignas(16) _Float16 HH[16][136];     // h (128)
    __shared__ alignas(16) _Float16 XB[2][16][72];   // x (64), double-buffered
    __shared__ alignas(16) _Float16 ZB[16][40];      // z_gen (32)
    __shared__ alignas(16) _Float16 XG[16][72];      // x_gen (64)
    // gi x-part B-tiles, pre-swizzled per-lane: [gw][gate][kt][lane] -> 48 KB
    __shared__ alignas(16) f16x8 GIX[8][3][2][64];

    const int t = threadIdx.x;
    const int w = t >> 6, l = t & 63;
    const int g4 = l >> 4, li = l & 15;
    const int n0 = blockIdx.x * BROWS;

    f16x8 WB[12];                 // per-role register B-tiles
    f16x8 wgiz[3];                // gate-waves: gi z-part tiles
    f32x4 accM = {0,0,0,0}, accR = {0,0,0,0};
    f32x4 agh[3], agi[3];
    float hprev[4] = {0,0,0,0};
    float ezc[4] = {0,0,0,0}, ezn[4] = {0,0,0,0};
    float exc[4] = {0,0,0,0}, exn[4] = {0,0,0,0};
    float b0 = 0.f, b1 = 0.f, bi[3] = {0,0,0}, bh[3] = {0,0,0};
    int u = 0;

    // ---------------- prologue: pack weights, init state ----------------
    if (w < 8) {                               // gate-waves
        u = 16 * w + li;
#pragma unroll
        for (int g = 0; g < 3; ++g) {
#pragma unroll
            for (int kt = 0; kt < 4; ++kt)
                WB[g * 4 + kt] = pack_tile(Whh, 384, kt * 32, g * 128 + u, g4);
            wgiz[g] = pack_tile(Wih, 384, 64, g * 128 + u, g4);
#pragma unroll
            for (int kt = 0; kt < 2; ++kt)
                GIX[w][g][kt][l] = pack_tile(Wih, 384, kt * 32, g * 128 + u, g4);
            bi[g] = bih[g * 128 + u]; bh[g] = bhh[g * 128 + u];
        }
#pragma unroll
        for (int r = 0; r < 4; ++r) HH[4 * g4 + r][u] = (_Float16)0.f;
    } else if (w < 10) {                       // qzcx-waves
        u = 16 * (w - 8) + li;
#pragma unroll
        for (int kt = 0; kt < 6; ++kt) {
            WB[kt]     = pack_tile(Wq, 64, kt * 32, u, g4);
            WB[6 + kt] = pack_tile(Wq, 64, kt * 32, 32 + u, g4);
        }
        b0 = bq[u]; b1 = bq[32 + u];
#pragma unroll
        for (int r = 0; r < 4; ++r) ezc[r] = EZ[(n0 + 4 * g4 + r) * LAT + u];
    } else if (w < 14) {                       // pxcz-waves
        u = 16 * (w - 10) + li;
#pragma unroll
        for (int kt = 0; kt < 5; ++kt) {
            WB[kt]     = pack_tile(Wp, 128, kt * 32, u, g4);
            WB[5 + kt] = pack_tile(Wp, 128, kt * 32, 64 + u, g4);
        }
        b0 = bp[u]; b1 = bp[64 + u];
#pragma unroll
        for (int r = 0; r < 4; ++r) exc[r] = EX[(n0 + 4 * g4 + r) * IN + u];
    } else {                                   // stage-waves: X step 0
        const int idx = (w - 14) * 64 + l, row = idx >> 3, seg = idx & 7;
        const float* src = X + (size_t)(n0 + row) * (LSTEPS * IN) + seg * 8;
        float4 f0 = *(const float4*)(src);
        float4 f1 = *(const float4*)(src + 4);
        f16x8 o;
        o[0]=(_Float16)f0.x; o[1]=(_Float16)f0.y; o[2]=(_Float16)f0.z; o[3]=(_Float16)f0.w;
        o[4]=(_Float16)f1.x; o[5]=(_Float16)f1.y; o[6]=(_Float16)f1.z; o[7]=(_Float16)f1.w;
        *(f16x8*)&XB[0][row][seg * 8] = o;
    }
    __syncthreads();

    for (int l_s = 0; l_s < LSTEPS; ++l_s) {
        // ---------------- Phase A ----------------
        if (w < 8) {
            f16x8 a0 = *(const f16x8*)&HH[li][8 * g4];
            f16x8 a1 = *(const f16x8*)&HH[li][32 + 8 * g4];
            f16x8 a2 = *(const f16x8*)&HH[li][64 + 8 * g4];
            f16x8 a3 = *(const f16x8*)&HH[li][96 + 8 * g4];
#pragma unroll
            for (int g = 0; g < 3; ++g) {
                f32x4 acc = {0,0,0,0};
                acc = MF(a0, WB[g * 4 + 0], acc);
                acc = MF(a1, WB[g * 4 + 1], acc);
                acc = MF(a2, WB[g * 4 + 2], acc);
                acc = MF(a3, WB[g * 4 + 3], acc);
                agh[g] = acc;
            }
        } else if (w < 10) {
            if (l_s + 1 < LSTEPS) {
#pragma unroll
                for (int r = 0; r < 4; ++r)
                    ezn[r] = EZ[(size_t)(l_s + 1) * (NROWS * LAT) + (n0 + 4 * g4 + r) * LAT + u];
            }
            f16x8 x0 = *(const f16x8*)&XB[l_s & 1][li][8 * g4];
            f16x8 x1 = *(const f16x8*)&XB[l_s & 1][li][32 + 8 * g4];
            f16x8 h0 = *(const f16x8*)&HH[li][8 * g4];
            f16x8 h1 = *(const f16x8*)&HH[li][32 + 8 * g4];
            f16x8 h2 = *(const f16x8*)&HH[li][64 + 8 * g4];
            f16x8 h3 = *(const f16x8*)&HH[li][96 + 8 * g4];
            f32x4 am = {0,0,0,0}, ar = {0,0,0,0};
            am = MF(x0, WB[0], am);  ar = MF(x0, WB[6],  ar);
            am = MF(x1, WB[1], am);  ar = MF(x1, WB[7],  ar);
            am = MF(h0, WB[2], am);  ar = MF(h0, WB[8],  ar);
            am = MF(h1, WB[3], am);  ar = MF(h1, WB[9],  ar);
            am = MF(h2, WB[4], am);  ar = MF(h2, WB[10], ar);
            am = MF(h3, WB[5], am);  ar = MF(h3, WB[11], ar);
#pragma unroll
            for (int r = 0; r < 4; ++r) {
                float z = (am[r] + b0) + fast_softplus(ar[r] + b1) * ezc[r];
                ZB[4 * g4 + r][u] = (_Float16)z;
                ezc[r] = ezn[r];
            }
        } else if (w < 14) {
            if (l_s + 1 < LSTEPS) {
#pragma unroll
                for (int r = 0; r < 4; ++r)
                    exn[r] = EX[(size_t)(l_s + 1) * (NROWS * IN) + (n0 + 4 * g4 + r) * IN + u];
            }
            f16x8 h0 = *(const f16x8*)&HH[li][8 * g4];
            f16x8 h1 = *(const f16x8*)&HH[li][32 + 8 * g4];
            f16x8 h2 = *(const f16x8*)&HH[li][64 + 8 * g4];
            f16x8 h3 = *(const f16x8*)&HH[li][96 + 8 * g4];
            f32x4 am = {0,0,0,0}, ar = {0,0,0,0};
            am = MF(h0, WB[1], am);  ar = MF(h0, WB[6], ar);
            am = MF(h1, WB[2], am);  ar = MF(h1, WB[7], ar);
            am = MF(h2, WB[3], am);  ar = MF(h2, WB[8], ar);
            am = MF(h3, WB[4], am);  ar = MF(h3, WB[9], ar);
            accM = am; accR = ar;
        } else {
            if (l_s + 1 < LSTEPS) {
                const int idx = (w - 14) * 64 + l, row = idx >> 3, seg = idx & 7;
                const float* src = X + (size_t)(n0 + row) * (LSTEPS * IN) + (l_s + 1) * IN + seg * 8;
                float4 f0 = *(const float4*)(src);
                float4 f1 = *(const float4*)(src + 4);
                f16x8 o;
                o[0]=(_Float16)f0.x; o[1]=(_Float16)f0.y; o[2]=(_Float16)f0.z; o[3]=(_Float16)f0.w;
                o[4]=(_Float16)f1.x; o[5]=(_Float16)f1.y; o[6]=(_Float16)f1.z; o[7]=(_Float16)f1.w;
                *(f16x8*)&XB[(l_s + 1) & 1][row][seg * 8] = o;
            }
        }
        __syncthreads();

        // ---------------- Phase B ----------------
        if (w < 8) {
            f16x8 az = *(const f16x8*)&ZB[li][8 * g4];
#pragma unroll
            for (int g = 0; g < 3; ++g) {
                f32x4 acc = {0,0,0,0};
                agi[g] = MF(az, wgiz[g], acc);
            }
        } else if (w >= 10 && w < 14) {
            f16x8 az = *(const f16x8*)&ZB[li][8 * g4];
            f32x4 am = MF(az, WB[0], accM);
            f32x4 ar = MF(az, WB[5], accR);
#pragma unroll
            for (int r = 0; r < 4; ++r) {
                float xg = (am[r] + b0) + fast_softplus(ar[r] + b1) * exc[r];
                XG[4 * g4 + r][u] = (_Float16)xg;
                exc[r] = exn[r];
            }
        }
        __syncthreads();

        // ---------------- Phase C: gi_x + gates ----------------
        if (w < 8) {
            f16x8 ax0 = *(const f16x8*)&XG[li][8 * g4];
            f16x8 ax1 = *(const f16x8*)&XG[li][32 + 8 * g4];
#pragma unroll
            for (int g = 0; g < 3; ++g) {
                agi[g] = MF(ax0, GIX[w][g][0][l], agi[g]);
                agi[g] = MF(ax1, GIX[w][g][1][l], agi[g]);
            }
#pragma unroll
            for (int r = 0; r < 4; ++r) {
                float gir = agi[0][r] + bi[0], ghr = agh[0][r] + bh[0];
                float giz = agi[1][r] + bi[1], ghz = agh[1][r] + bh[1];
                float gin = agi[2][r] + bi[2], ghn = agh[2][r] + bh[2];
                float rr = fast_sigmoid(gir + ghr);
                float zg = fast_sigmoid(giz + ghz);
                float nn = fast_tanh(fmaf(rr, ghn, gin));
                float h = fmaf(zg, hprev[r] - nn, nn);   // (1-z)*n + z*h
                hprev[r] = h;
                HH[4 * g4 + r][u] = (_Float16)h;
                out[(size_t)(n0 + 4 * g4 + r) * (LSTEPS * HID) + (size_t)l_s * HID + u] = h;
            }
        }
        __syncthreads();
    }

    // hs_final[0, n, :]
    if (w < 8) {
#pragma unroll
        for (int r = 0; r < 4; ++r)
            out[(size_t)NROWS * LSTEPS * HID + (size_t)(n0 + 4 * g4 + r) * HID + u] = hprev[r];
    }
}

extern "C" void kernel_launch(void* const* d_in, const int* in_sizes, int n_in,
                              void* d_out, int out_size, void* d_ws, size_t ws_size,
                              hipStream_t stream) {
    const float* X   = (const float*)d_in[0];
    const float* EZ  = (const float*)d_in[1];
    const float* EX  = (const float*)d_in[2];
    const float* Wq  = (const float*)d_in[3];
    const float* bq  = (const float*)d_in[4];
    const float* Wp  = (const float*)d_in[5];
    const float* bp  = (const float*)d_in[6];
    const float* Wih = (const float*)d_in[7];
    const float* Whh = (const float*)d_in[8];
    const float* bih = (const float*)d_in[9];
    const float* bhh = (const float*)d_in[10];
    float* out = (float*)d_out;

    vrnn_kernel<<<dim3(NBLK), dim3(1024), 0, stream>>>(
        X, EZ, EX, Wq, bq, Wp, bp, Wih, Whh, bih, bhh, out);
}

// Round 8
// 1018.892 us; speedup vs baseline: 2.1097x; 2.1097x over previous
//
#include <hip/hip_runtime.h>

namespace {

constexpr int NROWS = 256, LSTEPS = 512, IN = 64, LAT = 32, HID = 128;

typedef _Float16 h2 __attribute__((ext_vector_type(2)));
typedef _Float16 h8 __attribute__((ext_vector_type(8)));

__device__ __forceinline__ float fast_sigmoid(float x) {
    return __fdividef(1.f, 1.f + __expf(-x));
}
__device__ __forceinline__ float fast_softplus(float x) {
    return fmaxf(x, 0.f) + __logf(1.f + __expf(-fabsf(x)));
}
__device__ __forceinline__ float fast_tanh(float x) {
    float e = __expf(-2.f * fabsf(x));
    return copysignf(__fdividef(1.f - e, 1.f + e), x);
}
__device__ __forceinline__ float dot2f(h2 w, h2 a, float c) {
#if __has_builtin(__builtin_amdgcn_fdot2)
    return __builtin_amdgcn_fdot2(w, a, c, false);
#else
    return fmaf((float)w[0], (float)a[0], fmaf((float)w[1], (float)a[1], c));
#endif
}
__device__ __forceinline__ h2 packw(float a, float b) {
    h2 r; r[0] = (_Float16)a; r[1] = (_Float16)b; return r;
}

// LDS-only barrier: drain lgkmcnt (LDS writes/reads, shfl) but leave global
// loads/stores pending in vmcnt. __syncthreads() would drain vmcnt(0) too,
// putting ~900-cycle HBM prefetch latency on the critical path 4x/step.
__device__ __forceinline__ void soft_barrier() {
    asm volatile("s_waitcnt lgkmcnt(0)\n\ts_barrier" ::: "memory");
}

// NPAIR f16x2 register weights vs 2*NPAIR f16 LDS activations, 4 split accs.
template<int BASE, int NPAIR>
__device__ __forceinline__ float dotp2(const _Float16* act, const h2 (&w)[60], float init) {
    float a0 = init, a1 = 0.f, a2 = 0.f, a3 = 0.f;
#pragma unroll
    for (int i = 0; i < NPAIR / 4; ++i) {
        h8 b = *(const h8*)(act + 8 * i);
        a0 = dot2f(w[BASE + 4 * i + 0], __builtin_shufflevector(b, b, 0, 1), a0);
        a1 = dot2f(w[BASE + 4 * i + 1], __builtin_shufflevector(b, b, 2, 3), a1);
        a2 = dot2f(w[BASE + 4 * i + 2], __builtin_shufflevector(b, b, 4, 5), a2);
        a3 = dot2f(w[BASE + 4 * i + 3], __builtin_shufflevector(b, b, 6, 7), a3);
    }
    return (a0 + a1) + (a2 + a3);
}

} // namespace

// 1024 threads = 16 waves = 4 waves/SIMD. One block per batch row.
// waves_per_eu(4,4) -> 128-VGPR budget so wpk[60] stays in arch VGPRs
// (R6 profile showed VGPR_Count=64: weights got shunted to AGPRs, doubling
// the VALU stream with v_accvgpr_read per dot2).
// 4-phase schedule:
//  A: pxcz_h (X) + qzcx->z (Y, shfl-reduce) + gh slots 0,1 (all)
//  B: pxcz_z -> x_gen (X, shfl-reduce) + gi_z (Y) + gh slot 2 (all)
//  D: gi_x (all) + next-x refresh
//  G: GRU gates (t<128)
__global__ __launch_bounds__(1024)
__attribute__((amdgpu_waves_per_eu(4, 4)))
void vrnn_kernel(
    const float* __restrict__ X, const float* __restrict__ EZ, const float* __restrict__ EX,
    const float* __restrict__ Wq, const float* __restrict__ bq,
    const float* __restrict__ Wp, const float* __restrict__ bp,
    const float* __restrict__ Wih, const float* __restrict__ Whh,
    const float* __restrict__ bih, const float* __restrict__ bhh,
    float* __restrict__ out)
{
    __shared__ alignas(16) _Float16 XH[192];        // [ x(64) | h(128) ]
    __shared__ alignas(16) _Float16 ZH[32];         // z_gen
    __shared__ alignas(16) _Float16 XZ[64];         // x_gen
    __shared__ alignas(16) float gi_part[384][12];  // [0:4) x-quarters, [4:6) z-halves
    __shared__ alignas(16) float gh_part[384][12];  // [0:8) h-eighths

    const int t = threadIdx.x;
    const int n = blockIdx.x;
    const int y = t - 512;

    h2 wpk[60];

    // gh slices: X covers s in [0,1536): s=3t+i. Y covers [1536,3072): s=1536+3y+i.
    int mh[3], k8h[3];
#pragma unroll
    for (int i = 0; i < 3; ++i) {
        int s = (t < 512) ? (3 * t + i) : (1536 + 3 * y + i);
        mh[i] = s >> 3; k8h[i] = s & 7;
    }
    // gi_x slices (1536 slots: s=t | 512+y | 1024+t)
    int mxA = 0, kxA = 0, mxB = 0, kxB = 0;
    if (t < 512) { mxA = t >> 2; kxA = t & 3; int s = 1024 + t; mxB = s >> 2; kxB = s & 3; }
    else         { int s = 512 + y; mxA = s >> 2; kxA = s & 3; }
    // gi_z slices (Y: 768 slots: s=y | 512+y for y<256)
    int mzA = 0, kzA = 0, mzB = 0, kzB = 0;
    if (t >= 512) { mzA = y >> 1; kzA = y & 1; int s = 512 + y; mzB = s >> 1; kzB = s & 1; }

    // ---------------- one-time weight load into registers ----------------
    if (t < 512) {
        const int j = t >> 3, mr = (t >> 2) & 1, kq = t & 3;
        const int o = j + mr * 64;                 // pxcz col (mean j / raw j+64)
#pragma unroll
        for (int p = 0; p < 16; ++p) { int k = 32 + kq * 32 + 2 * p;
            wpk[p] = packw(Wp[k * 128 + o], Wp[(k + 1) * 128 + o]); }
#pragma unroll
        for (int p = 0; p < 4; ++p) { int k = kq * 8 + 2 * p;
            wpk[16 + p] = packw(Wp[k * 128 + o], Wp[(k + 1) * 128 + o]); }
#pragma unroll
        for (int i = 0; i < 3; ++i)
#pragma unroll
            for (int p = 0; p < 8; ++p) { int k = 16 * k8h[i] + 2 * p;
                wpk[20 + 8 * i + p] = packw(Whh[k * 384 + mh[i]], Whh[(k + 1) * 384 + mh[i]]); }
#pragma unroll
        for (int p = 0; p < 8; ++p) { int k = 16 * kxA + 2 * p;
            wpk[44 + p] = packw(Wih[k * 384 + mxA], Wih[(k + 1) * 384 + mxA]); }
#pragma unroll
        for (int p = 0; p < 8; ++p) { int k = 16 * kxB + 2 * p;
            wpk[52 + p] = packw(Wih[k * 384 + mxB], Wih[(k + 1) * 384 + mxB]); }
    } else {
        const int j = y >> 4, mr = (y >> 3) & 1, k3 = y & 7;
        const int o = j + mr * 32;                 // qzcx col
#pragma unroll
        for (int p = 0; p < 12; ++p) { int k = 24 * k3 + 2 * p;
            wpk[p] = packw(Wq[k * 64 + o], Wq[(k + 1) * 64 + o]); }
#pragma unroll
        for (int i = 0; i < 3; ++i)
#pragma unroll
            for (int p = 0; p < 8; ++p) { int k = 16 * k8h[i] + 2 * p;
                wpk[12 + 8 * i + p] = packw(Whh[k * 384 + mh[i]], Whh[(k + 1) * 384 + mh[i]]); }
#pragma unroll
        for (int p = 0; p < 8; ++p) { int k = 64 + 16 * kzA + 2 * p;
            wpk[36 + p] = packw(Wih[k * 384 + mzA], Wih[(k + 1) * 384 + mzA]); }
        if (y < 256) {
#pragma unroll
            for (int p = 0; p < 8; ++p) { int k = 64 + 16 * kzB + 2 * p;
                wpk[44 + p] = packw(Wih[k * 384 + mzB], Wih[(k + 1) * 384 + mzB]); }
        }
#pragma unroll
        for (int p = 0; p < 8; ++p) { int k = 16 * kxA + 2 * p;
            wpk[52 + p] = packw(Wih[k * 384 + mxA], Wih[(k + 1) * 384 + mxA]); }
    }

    // ---------------- per-role biases ----------------
    float bqm = 0.f, bqr = 0.f, bpm = 0.f, bpr = 0.f;
    float bir = 0.f, biz = 0.f, bin_ = 0.f, bhr = 0.f, bhz = 0.f, bhn = 0.f;
    if (t >= 512 && (y & 15) == 0) { bqm = bq[y >> 4]; bqr = bq[(y >> 4) + 32]; }
    if (t < 512 && (t & 7) == 0)   { bpm = bp[t >> 3]; bpr = bp[(t >> 3) + 64]; }
    if (t < 128) { bir = bih[t]; biz = bih[128 + t]; bin_ = bih[256 + t];
                   bhr = bhh[t]; bhz = bhh[128 + t]; bhn = bhh[256 + t]; }

    const float* Xrow = X + n * (LSTEPS * IN);
    float* orow = out + n * (LSTEPS * HID);
    float hreg = 0.f;
    if (t < 128) XH[64 + t] = (_Float16)0.f;
    if (t < 64)  XH[t] = (_Float16)Xrow[t];

    float ez_nxt = 0.f, ex_nxt = 0.f, xn_nxt = 0.f;
    if (t >= 512 && (y & 15) == 0) ez_nxt = EZ[n * LAT + (y >> 4)];
    if (t < 512 && (t & 7) == 0)   ex_nxt = EX[n * IN + (t >> 3)];
    __syncthreads();   // full barrier once after prologue (drains weight loads)

    float ph = 0.f;   // pxcz h-part partial, carried A -> B

    for (int l = 0; l < LSTEPS; ++l) {
        const float ez_cur = ez_nxt, ex_cur = ex_nxt;
        if (l + 1 < LSTEPS) {
            if (t >= 512 && (y & 15) == 0) ez_nxt = EZ[(l + 1) * (NROWS * LAT) + n * LAT + (y >> 4)];
            if (t < 512 && (t & 7) == 0)   ex_nxt = EX[(l + 1) * (NROWS * IN) + n * IN + (t >> 3)];
            if (t < 64) xn_nxt = Xrow[(l + 1) * IN + t];
        }

        // ---------------- Phase A ----------------
        if (t < 512) {
            const int kq = t & 3;
            ph = dotp2<0, 16>(XH + 64 + 32 * kq, wpk, 0.f);            // pxcz_h
            float g0 = dotp2<20, 8>(XH + 64 + 16 * k8h[0], wpk, 0.f);
            float g1 = dotp2<28, 8>(XH + 64 + 16 * k8h[1], wpk, 0.f);
            gh_part[mh[0]][k8h[0]] = g0;
            gh_part[mh[1]][k8h[1]] = g1;
        } else {
            const int k3 = y & 7;
            float q = dotp2<0, 12>(XH + 24 * k3, wpk, 0.f);            // qzcx partial
            q += __shfl_xor(q, 1);
            q += __shfl_xor(q, 2);
            q += __shfl_xor(q, 4);
            float other = __shfl_xor(q, 8);                            // mean<->raw
            float g0 = dotp2<12, 8>(XH + 64 + 16 * k8h[0], wpk, 0.f);
            float g1 = dotp2<20, 8>(XH + 64 + 16 * k8h[1], wpk, 0.f);
            gh_part[mh[0]][k8h[0]] = g0;
            gh_part[mh[1]][k8h[1]] = g1;
            if ((y & 15) == 0) {
                float z = (q + bqm) + fast_softplus(other + bqr) * ez_cur;
                ZH[y >> 4] = (_Float16)z;
            }
        }
        soft_barrier();

        // ---------------- Phase B ----------------
        if (t < 512) {
            const int kq = t & 3;
            float tot = dotp2<16, 4>(ZH + 8 * kq, wpk, ph);            // + z-part
            tot += __shfl_xor(tot, 1);
            tot += __shfl_xor(tot, 2);
            float other = __shfl_xor(tot, 4);                          // mean<->raw
            float g2 = dotp2<36, 8>(XH + 64 + 16 * k8h[2], wpk, 0.f);
            gh_part[mh[2]][k8h[2]] = g2;
            if ((t & 7) == 0) {
                float xg = (tot + bpm) + fast_softplus(other + bpr) * ex_cur;
                XZ[t >> 3] = (_Float16)xg;
            }
        } else {
            float z0 = dotp2<36, 8>(ZH + 16 * kzA, wpk, 0.f);
            gi_part[mzA][4 + kzA] = z0;
            if (y < 256) {
                float z1 = dotp2<44, 8>(ZH + 16 * kzB, wpk, 0.f);
                gi_part[mzB][4 + kzB] = z1;
            }
            float g2 = dotp2<28, 8>(XH + 64 + 16 * k8h[2], wpk, 0.f);
            gh_part[mh[2]][k8h[2]] = g2;
        }
        soft_barrier();

        // ---------------- Phase D ----------------
        if (t < 512) {
            float x0 = dotp2<44, 8>(XZ + 16 * kxA, wpk, 0.f);
            float x1 = dotp2<52, 8>(XZ + 16 * kxB, wpk, 0.f);
            gi_part[mxA][kxA] = x0;
            gi_part[mxB][kxB] = x1;
            if (t < 64 && l + 1 < LSTEPS) XH[t] = (_Float16)xn_nxt;    // next x
        } else {
            float x2 = dotp2<52, 8>(XZ + 16 * kxA, wpk, 0.f);
            gi_part[mxA][kxA] = x2;
        }
        soft_barrier();

        // ---------------- Phase G: gates ----------------
        if (t < 128) {
            float4 a; float2 b2;
            a = *(const float4*)&gi_part[t][0];        b2 = *(const float2*)&gi_part[t][4];
            float gir = (a.x + a.y) + (a.z + a.w) + (b2.x + b2.y) + bir;
            a = *(const float4*)&gi_part[128 + t][0];  b2 = *(const float2*)&gi_part[128 + t][4];
            float giz = (a.x + a.y) + (a.z + a.w) + (b2.x + b2.y) + biz;
            a = *(const float4*)&gi_part[256 + t][0];  b2 = *(const float2*)&gi_part[256 + t][4];
            float gin = (a.x + a.y) + (a.z + a.w) + (b2.x + b2.y) + bin_;
            float4 c4, d4;
            c4 = *(const float4*)&gh_part[t][0];       d4 = *(const float4*)&gh_part[t][4];
            float ghr = ((c4.x + c4.y) + (c4.z + c4.w)) + ((d4.x + d4.y) + (d4.z + d4.w)) + bhr;
            c4 = *(const float4*)&gh_part[128 + t][0]; d4 = *(const float4*)&gh_part[128 + t][4];
            float ghz = ((c4.x + c4.y) + (c4.z + c4.w)) + ((d4.x + d4.y) + (d4.z + d4.w)) + bhz;
            c4 = *(const float4*)&gh_part[256 + t][0]; d4 = *(const float4*)&gh_part[256 + t][4];
            float ghn = ((c4.x + c4.y) + (c4.z + c4.w)) + ((d4.x + d4.y) + (d4.z + d4.w)) + bhn;
            float r  = fast_sigmoid(gir + ghr);
            float zg = fast_sigmoid(giz + ghz);
            float nn = fast_tanh(fmaf(r, ghn, gin));
            float hnew = fmaf(zg, hreg - nn, nn);      // (1-z)*n + z*h
            hreg = hnew;
            XH[64 + t] = (_Float16)hnew;
            orow[l * HID + t] = hnew;
        }
        soft_barrier();
    }

    if (t < 128) out[NROWS * LSTEPS * HID + n * HID + t] = hreg;
}

extern "C" void kernel_launch(void* const* d_in, const int* in_sizes, int n_in,
                              void* d_out, int out_size, void* d_ws, size_t ws_size,
                              hipStream_t stream) {
    const float* X   = (const float*)d_in[0];
    const float* EZ  = (const float*)d_in[1];
    const float* EX  = (const float*)d_in[2];
    const float* Wq  = (const float*)d_in[3];
    const float* bq  = (const float*)d_in[4];
    const float* Wp  = (const float*)d_in[5];
    const float* bp  = (const float*)d_in[6];
    const float* Wih = (const float*)d_in[7];
    const float* Whh = (const float*)d_in[8];
    const float* bih = (const float*)d_in[9];
    const float* bhh = (const float*)d_in[10];
    float* out = (float*)d_out;

    vrnn_kernel<<<dim3(NROWS), dim3(1024), 0, stream>>>(
        X, EZ, EX, Wq, bq, Wp, bp, Wih, Whh, bih, bhh, out);
}